// Round 1
// baseline (277.719 us; speedup 1.0000x reference)
//
#include <hip/hip_runtime.h>
#include <hip/hip_bf16.h>

#define B_     32
#define C_     256
#define T_     4096
#define NH_    8
#define DH_    64

__global__ __launch_bounds__(256) void k_prep(
    const float* __restrict__ query, const float* __restrict__ Wkv,
    const float* __restrict__ bkv, const float* __restrict__ Wq,
    const float* __restrict__ bq, float* __restrict__ qWt,
    float* __restrict__ qb) {
  const int n = blockIdx.x;
  const int b = blockIdx.y;
  const int t = threadIdx.x;
  __shared__ float qrow_s[C_];
  __shared__ float psum[4 * 64];
  __shared__ float qsh[64];
  __shared__ float pb_s[64];

  qrow_s[t] = query[(size_t)b * C_ + t];
  __syncthreads();

  {
    const int d = t & 63, ch = t >> 6;
    const float* wrow = Wq + (size_t)(n * DH_ + d) * C_ + ch * 64;
    const float* qr = qrow_s + ch * 64;
    float s = 0.f;
    #pragma unroll
    for (int c = 0; c < 64; c += 4) {
      float4 w = *(const float4*)(wrow + c);
      s += w.x * qr[c] + w.y * qr[c + 1] + w.z * qr[c + 2] + w.w * qr[c + 3];
    }
    psum[ch * 64 + d] = s;
  }
  __syncthreads();
  if (t < 64)
    qsh[t] = bq[n * DH_ + t] + psum[t] + psum[64 + t] + psum[128 + t] + psum[192 + t];
  __syncthreads();

  const float scale = 0.125f;
  {
    const float* wk = Wkv + (size_t)(n * DH_) * C_ + t;
    float acc = 0.f;
    #pragma unroll 8
    for (int dd = 0; dd < DH_; ++dd) acc += qsh[dd] * wk[(size_t)dd * C_];
    qWt[((size_t)b * C_ + t) * NH_ + n] = acc * scale;
  }
  if (t < 64) pb_s[t] = qsh[t] * bkv[n * DH_ + t];
  __syncthreads();
  if (t == 0) {
    float s = 0.f;
    #pragma unroll 8
    for (int dd = 0; dd < 64; ++dd) s += pb_s[dd];
    qb[b * NH_ + n] = s * scale;
  }
}

// 4-way channel split: quarter q covers channels q*64 .. q*64+63.
// grid (8 j-tiles, 4 quarters, B_) = 1024 blocks -> 4 waves/SIMD.
__global__ __launch_bounds__(256) void k_logits(
    const float* __restrict__ x, const float* __restrict__ qWt,
    const float* __restrict__ qbv, float* __restrict__ lgpart) {
  const int q = blockIdx.y;      // channel quarter
  const int b = blockIdx.z;
  const int t = threadIdx.x;
  const int j = blockIdx.x * 512 + t * 2;
  __shared__ float qws[64 * NH_];

  if (t < 128) {
    const float4 v = *(const float4*)(qWt + (size_t)b * (C_ * NH_) + q * 64 * NH_ + t * 4);
    *(float4*)(qws + t * 4) = v;
  }
  __syncthreads();

  const float* xb = x + ((size_t)b * C_ + q * 64) * T_ + j;
  const float* qb = qbv + b * NH_;

  float acc0[NH_], acc1[NH_];
  #pragma unroll
  for (int n = 0; n < NH_; ++n) {
    const float init = (q == 0) ? qb[n] : 0.f;
    acc0[n] = init; acc1[n] = init;
  }

  for (int c0 = 0; c0 < 64; c0 += 8) {
    float2 xv[8];
    #pragma unroll
    for (int cc = 0; cc < 8; ++cc)
      xv[cc] = *(const float2*)(xb + (size_t)(c0 + cc) * T_);
    #pragma unroll
    for (int cc = 0; cc < 8; ++cc) {
      const float4 w0 = *(const float4*)(qws + (c0 + cc) * 8);
      const float4 w1 = *(const float4*)(qws + (c0 + cc) * 8 + 4);
      acc0[0] += w0.x * xv[cc].x; acc1[0] += w0.x * xv[cc].y;
      acc0[1] += w0.y * xv[cc].x; acc1[1] += w0.y * xv[cc].y;
      acc0[2] += w0.z * xv[cc].x; acc1[2] += w0.z * xv[cc].y;
      acc0[3] += w0.w * xv[cc].x; acc1[3] += w0.w * xv[cc].y;
      acc0[4] += w1.x * xv[cc].x; acc1[4] += w1.x * xv[cc].y;
      acc0[5] += w1.y * xv[cc].x; acc1[5] += w1.y * xv[cc].y;
      acc0[6] += w1.z * xv[cc].x; acc1[6] += w1.z * xv[cc].y;
      acc0[7] += w1.w * xv[cc].x; acc1[7] += w1.w * xv[cc].y;
    }
  }

  float* lg = lgpart + (((size_t)q * B_ + b) * NH_) * T_ + j;
  #pragma unroll
  for (int n = 0; n < NH_; ++n) {
    float2 o; o.x = acc0[n]; o.y = acc1[n];
    *(float2*)(lg + (size_t)n * T_) = o;
  }
}

__global__ __launch_bounds__(256) void k_softmax(
    const float* __restrict__ lgpart, float* __restrict__ attn) {
  const size_t row = blockIdx.x;
  const float* p0 = lgpart + row * T_;
  const float* p1 = lgpart + ((size_t)B_ * NH_ + row) * T_;
  const float* p2 = lgpart + ((size_t)2 * B_ * NH_ + row) * T_;
  const float* p3 = lgpart + ((size_t)3 * B_ * NH_ + row) * T_;
  float* pa = attn + row * T_;
  const int t = threadIdx.x;
  float4 v[4];
  #pragma unroll
  for (int i = 0; i < 4; ++i) {
    const int off = t * 4 + i * 1024;
    float4 a = *(const float4*)(p0 + off);
    float4 c = *(const float4*)(p1 + off);
    float4 d = *(const float4*)(p2 + off);
    float4 e = *(const float4*)(p3 + off);
    v[i].x = a.x + c.x + d.x + e.x;
    v[i].y = a.y + c.y + d.y + e.y;
    v[i].z = a.z + c.z + d.z + e.z;
    v[i].w = a.w + c.w + d.w + e.w;
  }

  float m = -3.4e38f;
  #pragma unroll
  for (int i = 0; i < 4; ++i)
    m = fmaxf(m, fmaxf(fmaxf(v[i].x, v[i].y), fmaxf(v[i].z, v[i].w)));
  #pragma unroll
  for (int o = 32; o >= 1; o >>= 1) m = fmaxf(m, __shfl_xor(m, o));
  __shared__ float sm[4];
  if ((t & 63) == 0) sm[t >> 6] = m;
  __syncthreads();
  m = fmaxf(fmaxf(sm[0], sm[1]), fmaxf(sm[2], sm[3]));

  float s = 0.f;
  #pragma unroll
  for (int i = 0; i < 4; ++i) {
    v[i].x = expf(v[i].x - m); v[i].y = expf(v[i].y - m);
    v[i].z = expf(v[i].z - m); v[i].w = expf(v[i].w - m);
    s += v[i].x + v[i].y + v[i].z + v[i].w;
  }
  #pragma unroll
  for (int o = 32; o >= 1; o >>= 1) s += __shfl_xor(s, o);
  __shared__ float ss[4];
  if ((t & 63) == 0) ss[t >> 6] = s;
  __syncthreads();
  s = ss[0] + ss[1] + ss[2] + ss[3];
  const float inv = 1.0f / s;

  #pragma unroll
  for (int i = 0; i < 4; ++i) {
    v[i].x *= inv; v[i].y *= inv; v[i].z *= inv; v[i].w *= inv;
    *(float4*)(pa + t * 4 + i * 1024) = v[i];
  }
}

// BJ 256->128: grid (32 j-tiles, B_) = 1024 blocks -> 4 waves/SIMD.
// part[b][jt=32][n=8][c=256]
#define BJ_  128
#define BJS_ 32
#define XPITCH_ 33
__global__ __launch_bounds__(256) void k_xattn(
    const float* __restrict__ x, const float* __restrict__ attn,
    float* __restrict__ part) {
  const int jt = blockIdx.x;
  const int b  = blockIdx.y;
  const int j0 = jt * BJ_;
  const int t  = threadIdx.x;
  __shared__ float xs[C_ * XPITCH_];

  const float* xb = x + (size_t)b * C_ * T_;
  const float* ab = attn + (size_t)b * NH_ * T_ + j0;  // uniform base

  float acc[NH_];
  #pragma unroll
  for (int n = 0; n < NH_; ++n) acc[n] = 0.f;

  const int cr = t >> 3;
  const int jc = (t & 7) * 4;

  for (int sIt = 0; sIt < BJ_ / BJS_; ++sIt) {
    const int js = sIt * BJS_;
    __syncthreads();
    #pragma unroll
    for (int p = 0; p < 8; ++p) {
      const int c = cr + p * 32;
      float4 vv = *(const float4*)(xb + (size_t)c * T_ + j0 + js + jc);
      float* dst = &xs[c * XPITCH_ + jc];
      dst[0] = vv.x; dst[1] = vv.y; dst[2] = vv.z; dst[3] = vv.w;
    }
    __syncthreads();
    const float* xr = &xs[t * XPITCH_];
    #pragma unroll 4
    for (int jj = 0; jj < BJS_; ++jj) {
      const float xv = xr[jj];
      const int j = js + jj;  // wave-uniform
      #pragma unroll
      for (int n = 0; n < NH_; ++n)
        acc[n] += ab[(size_t)n * T_ + j] * xv;  // uniform -> scalar broadcast
    }
  }

  float* pb = part + ((size_t)b * 32 + jt) * (NH_ * C_);
  #pragma unroll
  for (int n = 0; n < NH_; ++n) pb[n * C_ + t] = acc[n];
}

// Fused outv + fc: one block per batch, 512 threads.
// phase1: xa[n][c] = sum_jt part ; phase2: outv[o] = bkv_v[o] + Wkv_v[o]·xa ;
// phase3: out = relu(Wfc·outv + bfc)
__global__ __launch_bounds__(512) void k_out(
    const float* __restrict__ part, const float* __restrict__ Wkv,
    const float* __restrict__ bkv, const float* __restrict__ Wfc,
    const float* __restrict__ bfc, float* __restrict__ out) {
  __shared__ float xa_s[NH_ * C_];   // 2048 floats
  __shared__ float ov_s[512];
  const int b = blockIdx.x;
  const int t = threadIdx.x;

  const float* pb = part + (size_t)b * 32 * (NH_ * C_);
  #pragma unroll
  for (int r = 0; r < 4; ++r) {
    const int idx = r * 512 + t;
    float s = 0.f;
    #pragma unroll
    for (int jt = 0; jt < 32; ++jt) s += pb[(size_t)jt * (NH_ * C_) + idx];
    xa_s[idx] = s;
  }
  __syncthreads();

  {
    const int o = t;                              // 0..511
    const float* wrow = Wkv + (size_t)(512 + o) * C_;
    const float* xa = &xa_s[(o >> 6) * C_];       // head = o>>6
    float s = bkv[512 + o];
    #pragma unroll 8
    for (int c = 0; c < C_; c += 4) {
      float4 w = *(const float4*)(wrow + c);
      s += w.x * xa[c] + w.y * xa[c + 1] + w.z * xa[c + 2] + w.w * xa[c + 3];
    }
    ov_s[o] = s;
  }
  __syncthreads();

  if (t < 256) {
    const float* wrow = Wfc + (size_t)t * 512;
    float s = bfc[t];
    #pragma unroll 8
    for (int o = 0; o < 512; o += 4) {
      float4 w = *(const float4*)(wrow + o);
      s += w.x * ov_s[o] + w.y * ov_s[o + 1] + w.z * ov_s[o + 2] + w.w * ov_s[o + 3];
    }
    out[(size_t)b * 256 + t] = fmaxf(s, 0.f);
  }
}

extern "C" void kernel_launch(void* const* d_in, const int* in_sizes, int n_in,
                              void* d_out, int out_size, void* d_ws, size_t ws_size,
                              hipStream_t stream) {
  const float* x     = (const float*)d_in[0];
  const float* query = (const float*)d_in[1];
  const float* Wkv   = (const float*)d_in[2];
  const float* bkv   = (const float*)d_in[3];
  const float* Wq    = (const float*)d_in[4];
  const float* bq    = (const float*)d_in[5];
  const float* Wfc   = (const float*)d_in[6];
  const float* bfc   = (const float*)d_in[7];
  float* out = (float*)d_out;
  float* ws  = (float*)d_ws;

  float* qWt    = ws;                  // 65536
  float* qb     = ws + 65536;          // 256 (pad to 512)
  float* lgpart = ws + 66048;          // 4 * 1048576 = 4194304
  float* attn   = ws + 4260352;        // 1048576
  float* part   = ws + 5308928;        // 32*8*256*B_ = 2097152
  // total: 7406080 floats = 29.6 MB (ws is 512 MiB per fill-size evidence)

  k_prep   <<<dim3(NH_, B_),   256, 0, stream>>>(query, Wkv, bkv, Wq, bq, qWt, qb);
  k_logits <<<dim3(8, 4, B_),  256, 0, stream>>>(x, qWt, qb, lgpart);
  k_softmax<<<B_ * NH_,        256, 0, stream>>>(lgpart, attn);
  k_xattn  <<<dim3(32, B_),    256, 0, stream>>>(x, attn, part);
  k_out    <<<B_,              512, 0, stream>>>(part, Wkv, bkv, Wfc, bfc, out);
}

// Round 2
// 259.574 us; speedup vs baseline: 1.0699x; 1.0699x over previous
//
#include <hip/hip_runtime.h>
#include <hip/hip_bf16.h>

#define B_     32
#define C_     256
#define T_     4096
#define NH_    8
#define DH_    64

__global__ __launch_bounds__(256) void k_prep(
    const float* __restrict__ query, const float* __restrict__ Wkv,
    const float* __restrict__ bkv, const float* __restrict__ Wq,
    const float* __restrict__ bq, float* __restrict__ qWt,
    float* __restrict__ qb) {
  const int n = blockIdx.x;
  const int b = blockIdx.y;
  const int t = threadIdx.x;
  __shared__ float qrow_s[C_];
  __shared__ float psum[4 * 64];
  __shared__ float qsh[64];
  __shared__ float pb_s[64];

  qrow_s[t] = query[(size_t)b * C_ + t];
  __syncthreads();

  {
    const int d = t & 63, ch = t >> 6;
    const float* wrow = Wq + (size_t)(n * DH_ + d) * C_ + ch * 64;
    const float* qr = qrow_s + ch * 64;
    float s = 0.f;
    #pragma unroll
    for (int c = 0; c < 64; c += 4) {
      float4 w = *(const float4*)(wrow + c);
      s += w.x * qr[c] + w.y * qr[c + 1] + w.z * qr[c + 2] + w.w * qr[c + 3];
    }
    psum[ch * 64 + d] = s;
  }
  __syncthreads();
  if (t < 64)
    qsh[t] = bq[n * DH_ + t] + psum[t] + psum[64 + t] + psum[128 + t] + psum[192 + t];
  __syncthreads();

  const float scale = 0.125f;
  {
    const float* wk = Wkv + (size_t)(n * DH_) * C_ + t;
    float acc = 0.f;
    #pragma unroll 8
    for (int dd = 0; dd < DH_; ++dd) acc += qsh[dd] * wk[(size_t)dd * C_];
    qWt[((size_t)b * C_ + t) * NH_ + n] = acc * scale;
  }
  if (t < 64) pb_s[t] = qsh[t] * bkv[n * DH_ + t];
  __syncthreads();
  if (t == 0) {
    float s = 0.f;
    #pragma unroll 8
    for (int dd = 0; dd < 64; ++dd) s += pb_s[dd];
    qb[b * NH_ + n] = s * scale;
  }
}

// Full-channel logits per block: grid (8 jt, B_) x 512 threads.
// Thread (th = t>>8 channel-half, tj = t&255 -> j pair). Halves combined via
// LDS, half-0 writes final logits (4 MB total) + per-segment softmax stats
// (m, sumexp) so the standalone softmax kernel can be deleted.
__global__ __launch_bounds__(512) void k_logits(
    const float* __restrict__ x, const float* __restrict__ qWt,
    const float* __restrict__ qbv, float* __restrict__ lgraw,
    float* __restrict__ stats) {
  const int jt = blockIdx.x;
  const int b  = blockIdx.y;
  const int t  = threadIdx.x;
  const int tj = t & 255;
  const int th = t >> 8;
  __shared__ float qws[C_ * NH_];     // 8 KB
  __shared__ float red[256 * 16];     // 16 KB half-1 partials
  __shared__ float sred[8][4];
  __shared__ float ssum[8][4];
  __shared__ float Msh[8];

  {
    const float4 v = *(const float4*)(qWt + (size_t)b * (C_ * NH_) + t * 4);
    *(float4*)(qws + t * 4) = v;
  }
  __syncthreads();

  const int j = jt * 512 + tj * 2;
  const float* xb = x + ((size_t)b * C_ + th * 128) * T_ + j;
  const float* qb = qbv + b * NH_;

  float acc0[NH_], acc1[NH_];
  #pragma unroll
  for (int n = 0; n < NH_; ++n) {
    const float init = (th == 0) ? qb[n] : 0.f;
    acc0[n] = init; acc1[n] = init;
  }

  for (int c0 = 0; c0 < 128; c0 += 16) {
    float2 xv[16];
    #pragma unroll
    for (int cc = 0; cc < 16; ++cc)
      xv[cc] = *(const float2*)(xb + (size_t)(c0 + cc) * T_);
    #pragma unroll
    for (int cc = 0; cc < 16; ++cc) {
      const float4 w0 = *(const float4*)(qws + (th * 128 + c0 + cc) * 8);
      const float4 w1 = *(const float4*)(qws + (th * 128 + c0 + cc) * 8 + 4);
      acc0[0] += w0.x * xv[cc].x; acc1[0] += w0.x * xv[cc].y;
      acc0[1] += w0.y * xv[cc].x; acc1[1] += w0.y * xv[cc].y;
      acc0[2] += w0.z * xv[cc].x; acc1[2] += w0.z * xv[cc].y;
      acc0[3] += w0.w * xv[cc].x; acc1[3] += w0.w * xv[cc].y;
      acc0[4] += w1.x * xv[cc].x; acc1[4] += w1.x * xv[cc].y;
      acc0[5] += w1.y * xv[cc].x; acc1[5] += w1.y * xv[cc].y;
      acc0[6] += w1.z * xv[cc].x; acc1[6] += w1.z * xv[cc].y;
      acc0[7] += w1.w * xv[cc].x; acc1[7] += w1.w * xv[cc].y;
    }
  }

  if (th == 1) {
    float* r = red + tj * 16;
    #pragma unroll
    for (int n = 0; n < NH_; ++n) { r[n] = acc0[n]; r[8 + n] = acc1[n]; }
  }
  __syncthreads();
  if (th == 0) {
    const float* r = red + tj * 16;
    #pragma unroll
    for (int n = 0; n < NH_; ++n) { acc0[n] += r[n]; acc1[n] += r[8 + n]; }
    float* lg = lgraw + ((size_t)b * NH_) * T_ + j;
    #pragma unroll
    for (int n = 0; n < NH_; ++n) {
      float2 o; o.x = acc0[n]; o.y = acc1[n];
      *(float2*)(lg + (size_t)n * T_) = o;
    }
  }

  // segment softmax stats (waves 0-3 hold final logits; all waves run the
  // shuffles, writes are guarded)
  #pragma unroll
  for (int n = 0; n < NH_; ++n) {
    float mv = fmaxf(acc0[n], acc1[n]);
    #pragma unroll
    for (int o = 32; o >= 1; o >>= 1) mv = fmaxf(mv, __shfl_xor(mv, o));
    if (th == 0 && (tj & 63) == 0) sred[n][tj >> 6] = mv;
  }
  __syncthreads();
  if (t < 8)
    Msh[t] = fmaxf(fmaxf(sred[t][0], sred[t][1]), fmaxf(sred[t][2], sred[t][3]));
  __syncthreads();
  #pragma unroll
  for (int n = 0; n < NH_; ++n) {
    float sv = (th == 0) ? (expf(acc0[n] - Msh[n]) + expf(acc1[n] - Msh[n])) : 0.f;
    #pragma unroll
    for (int o = 32; o >= 1; o >>= 1) sv += __shfl_xor(sv, o);
    if (th == 0 && (tj & 63) == 0) ssum[n][tj >> 6] = sv;
  }
  __syncthreads();
  if (t < 8) {
    const float S = ssum[t][0] + ssum[t][1] + ssum[t][2] + ssum[t][3];
    float2 o; o.x = Msh[t]; o.y = S;
    *(float2*)(stats + ((size_t)(b * NH_ + t) * 8 + jt) * 2) = o;
  }
}

// Inline-softmax xattn: grid (32 jt, B_) x 256. Prologue combines the 8
// segment stats (log-sum-exp); attn computed on the fly into LDS.
// part[b][jt=32][n=8][c=256]
#define BJ_  128
#define BJS_ 32
#define XPITCH_ 33
__global__ __launch_bounds__(256) void k_xattn(
    const float* __restrict__ x, const float* __restrict__ lgraw,
    const float* __restrict__ stats, float* __restrict__ part) {
  const int jt = blockIdx.x;
  const int b  = blockIdx.y;
  const int j0 = jt * BJ_;
  const int t  = threadIdx.x;
  __shared__ float xs[C_ * XPITCH_];
  __shared__ float a_lds[NH_][BJS_];
  __shared__ float Msh[NH_];
  __shared__ float Sish[NH_];

  if (t < NH_) {
    const float* st = stats + (size_t)(b * NH_ + t) * 8 * 2;
    float M = -3.4e38f;
    #pragma unroll
    for (int k = 0; k < 8; ++k) M = fmaxf(M, st[k * 2]);
    float S = 0.f;
    #pragma unroll
    for (int k = 0; k < 8; ++k) S += st[k * 2 + 1] * expf(st[k * 2] - M);
    Msh[t] = M; Sish[t] = 1.0f / S;
  }

  const float* xb  = x + (size_t)b * C_ * T_;
  const float* lgb = lgraw + (size_t)b * NH_ * T_ + j0;

  float acc[NH_];
  #pragma unroll
  for (int n = 0; n < NH_; ++n) acc[n] = 0.f;

  const int cr = t >> 3;
  const int jc = (t & 7) * 4;
  const int an = t >> 5;
  const int aj = t & 31;

  for (int sIt = 0; sIt < BJ_ / BJS_; ++sIt) {
    const int js = sIt * BJS_;
    __syncthreads();   // first iter: also orders Msh/Sish writes
    #pragma unroll
    for (int p = 0; p < 8; ++p) {
      const int c = cr + p * 32;
      float4 vv = *(const float4*)(xb + (size_t)c * T_ + j0 + js + jc);
      float* dst = &xs[c * XPITCH_ + jc];
      dst[0] = vv.x; dst[1] = vv.y; dst[2] = vv.z; dst[3] = vv.w;
    }
    {
      const float lv = lgb[(size_t)an * T_ + js + aj];
      a_lds[an][aj] = expf(lv - Msh[an]) * Sish[an];
    }
    __syncthreads();
    const float* xr = &xs[t * XPITCH_];
    #pragma unroll 4
    for (int jj = 0; jj < BJS_; ++jj) {
      const float xv = xr[jj];
      #pragma unroll
      for (int n = 0; n < NH_; ++n)
        acc[n] += a_lds[n][jj] * xv;   // broadcast LDS read
    }
  }

  float* pb = part + ((size_t)b * 32 + jt) * (NH_ * C_);
  #pragma unroll
  for (int n = 0; n < NH_; ++n) pb[n * C_ + t] = acc[n];
}

// Reduce part + v-projection: grid (NH_, B_) x 256 — 8x the old parallelism.
__global__ __launch_bounds__(256) void k_out2(
    const float* __restrict__ part, const float* __restrict__ Wkv,
    const float* __restrict__ bkv, float* __restrict__ outvG) {
  const int n = blockIdx.x;
  const int b = blockIdx.y;
  const int t = threadIdx.x;
  __shared__ float xa[C_];
  __shared__ float psum[4][64];

  {
    const float* pb = part + (size_t)b * 32 * (NH_ * C_) + n * C_ + t;
    float s = 0.f;
    #pragma unroll
    for (int jt = 0; jt < 32; ++jt) s += pb[(size_t)jt * (NH_ * C_)];
    xa[t] = s;
  }
  __syncthreads();

  {
    const int d = t & 63, q = t >> 6;
    const float* wrow = Wkv + (size_t)(512 + n * 64 + d) * C_ + q * 64;
    const float* xq = xa + q * 64;
    float s = 0.f;
    #pragma unroll
    for (int c = 0; c < 64; c += 4) {
      float4 w = *(const float4*)(wrow + c);
      s += w.x * xq[c] + w.y * xq[c + 1] + w.z * xq[c + 2] + w.w * xq[c + 3];
    }
    psum[q][d] = s;
  }
  __syncthreads();
  if (t < 64)
    outvG[(size_t)b * 512 + n * 64 + t] =
        bkv[512 + n * 64 + t] + psum[0][t] + psum[1][t] + psum[2][t] + psum[3][t];
}

__global__ __launch_bounds__(256) void k_fc(
    const float* __restrict__ outvG, const float* __restrict__ Wfc,
    const float* __restrict__ bfc, float* __restrict__ out) {
  __shared__ float ov[512];
  const int b = blockIdx.x;
  const int t = threadIdx.x;
  ov[t] = outvG[(size_t)b * 512 + t];
  ov[256 + t] = outvG[(size_t)b * 512 + 256 + t];
  __syncthreads();

  const float* wrow = Wfc + (size_t)t * 512;
  float s = bfc[t];
  #pragma unroll 8
  for (int o = 0; o < 512; o += 4) {
    float4 w = *(const float4*)(wrow + o);
    s += w.x * ov[o] + w.y * ov[o + 1] + w.z * ov[o + 2] + w.w * ov[o + 3];
  }
  out[(size_t)b * 256 + t] = fmaxf(s, 0.f);
}

extern "C" void kernel_launch(void* const* d_in, const int* in_sizes, int n_in,
                              void* d_out, int out_size, void* d_ws, size_t ws_size,
                              hipStream_t stream) {
  const float* x     = (const float*)d_in[0];
  const float* query = (const float*)d_in[1];
  const float* Wkv   = (const float*)d_in[2];
  const float* bkv   = (const float*)d_in[3];
  const float* Wq    = (const float*)d_in[4];
  const float* bq    = (const float*)d_in[5];
  const float* Wfc   = (const float*)d_in[6];
  const float* bfc   = (const float*)d_in[7];
  float* out = (float*)d_out;
  float* ws  = (float*)d_ws;

  float* qWt   = ws;                   // 65536 floats
  float* qb    = ws + 65536;           // 256 (pad 512)
  float* stats = ws + 66048;           // 32*8*8*2 = 4096
  float* lgraw = ws + 70144;           // 32*8*4096 = 1048576
  float* part  = ws + 1118720;         // 32*32*8*256 = 2097152
  float* outvG = ws + 3215872;         // 16384
  // total ~3.23 M floats = 12.9 MB

  k_prep   <<<dim3(NH_, B_), 256, 0, stream>>>(query, Wkv, bkv, Wq, bq, qWt, qb);
  k_logits <<<dim3(8, B_),   512, 0, stream>>>(x, qWt, qb, lgraw, stats);
  k_xattn  <<<dim3(32, B_),  256, 0, stream>>>(x, lgraw, stats, part);
  k_out2   <<<dim3(NH_, B_), 256, 0, stream>>>(part, Wkv, bkv, outvG);
  k_fc     <<<B_,            256, 0, stream>>>(outvG, Wfc, bfc, out);
}